// Round 4
// baseline (258.284 us; speedup 1.0000x reference)
//
#include <hip/hip_runtime.h>

// Antecedents: out[n, r] = prod_v memberships[v, n, s_v(r)]
// r = s0*4^5 + s1*4^4 + s2*4^3 + s3*4^2 + s4*4 + s5  (s5 fastest)
//
// memberships: [6, 16384, 4] fp32 (1.5 MB read); out: [16384, 4096] fp32
// (268 MB written) -> pure write-BW bound, roofline ~43 us @ 6.3 TB/s.
//
// R3 post-mortem: bench dur_us includes ~209 us of harness reset fills
// (1 GiB d_ws + 268 MB d_out poison); kernel itself is ~47 us. This round:
// drop LDS+barrier (block-uniform s_load of the 24 floats, per-lane
// v_cndmask select), grid-stride 8 samples/block for full occupancy and
// deeper store pipelining.

constexpr int N_SAMPLES = 16384;
constexpr int N_SETS    = 4;
constexpr int SPB       = 8;                       // samples per block
constexpr int VSTRIDE   = N_SAMPLES * N_SETS;      // floats per variable plane

typedef float v4f __attribute__((ext_vector_type(4)));

__device__ __forceinline__ float sel4(v4f v, int i) {
  float r = v.x;
  r = (i == 1) ? v.y : r;
  r = (i == 2) ? v.z : r;
  r = (i == 3) ? v.w : r;
  return r;  // compiles to a v_cndmask chain; operands are SGPR-resident
}

__global__ __launch_bounds__(256) void antecedents_kernel(
    const float* __restrict__ m, v4f* __restrict__ out4) {
  const int t  = threadIdx.x;          // 0..255
  const int n0 = blockIdx.x * SPB;

  // combo c = i*256 + t  ->  s0 = i, s1..s4 from t, s5 = float4 lane
  const int s1 = (t >> 6) & 3;
  const int s2 = (t >> 4) & 3;
  const int s3 = (t >> 2) & 3;
  const int s4 = t & 3;

#pragma unroll
  for (int j = 0; j < SPB; ++j) {
    const int n = n0 + j;  // block-uniform -> scalar loads below
    const v4f m0 = *reinterpret_cast<const v4f*>(m + 0 * VSTRIDE + n * N_SETS);
    const v4f m1 = *reinterpret_cast<const v4f*>(m + 1 * VSTRIDE + n * N_SETS);
    const v4f m2 = *reinterpret_cast<const v4f*>(m + 2 * VSTRIDE + n * N_SETS);
    const v4f m3 = *reinterpret_cast<const v4f*>(m + 3 * VSTRIDE + n * N_SETS);
    const v4f m4 = *reinterpret_cast<const v4f*>(m + 4 * VSTRIDE + n * N_SETS);
    const v4f m5 = *reinterpret_cast<const v4f*>(m + 5 * VSTRIDE + n * N_SETS);

    const float q = sel4(m1, s1) * sel4(m2, s2) * sel4(m3, s3) * sel4(m4, s4);
    const v4f qm5 = q * m5;

    v4f* dst = out4 + (size_t)n * 1024 + t;
    dst[0]   = m0.x * qm5;
    dst[256] = m0.y * qm5;
    dst[512] = m0.z * qm5;
    dst[768] = m0.w * qm5;
  }
}

extern "C" void kernel_launch(void* const* d_in, const int* in_sizes, int n_in,
                              void* d_out, int out_size, void* d_ws, size_t ws_size,
                              hipStream_t stream) {
  const float* m = (const float*)d_in[0];
  v4f* out = (v4f*)d_out;
  antecedents_kernel<<<N_SAMPLES / SPB, 256, 0, stream>>>(m, out);
}